// Round 1
// baseline (17905.745 us; speedup 1.0000x reference)
//
#include <hip/hip_runtime.h>
#include <math.h>

#define NN 100000
#define EIE 1600000
#define ECE 800000
#define GG 2000
#define FDIM 512
#define CC 128
#define BNEPS 1e-5f

static inline int cdiv(long a, long b){ return (int)((a+b-1)/b); }

// ---------------- degree count (inter edges) ----------------
__global__ void k_degrees(const int* __restrict__ src, const int* __restrict__ dst,
                          float* __restrict__ dout, float* __restrict__ din) {
  int e = blockIdx.x*256 + threadIdx.x;
  if (e < EIE) { atomicAdd(&dout[src[e]], 1.f); atomicAdd(&din[dst[e]], 1.f); }
}

// ---------------- GEMM: y[N,128] = x[N,FIN] @ W[FIN,128]; optional row scale dout^-1/2 ----
template<int FIN>
__global__ void k_gemm(const float* __restrict__ x, const float* __restrict__ W,
                       const float* __restrict__ rowdeg, float* __restrict__ y) {
  int col = threadIdx.x & 127;
  int row = blockIdx.x*2 + (threadIdx.x >> 7);
  if (row >= NN) return;
  const float* xr = x + (size_t)row*FIN;
  float acc = 0.f;
  #pragma unroll 2
  for (int k = 0; k < FIN; k += 4) {
    float4 xv = *(const float4*)(xr + k);
    acc += xv.x*W[(k+0)*CC+col];
    acc += xv.y*W[(k+1)*CC+col];
    acc += xv.z*W[(k+2)*CC+col];
    acc += xv.w*W[(k+3)*CC+col];
  }
  if (rowdeg) acc *= 1.0f/sqrtf(fmaxf(rowdeg[row],1.f));
  y[(size_t)row*CC+col] = acc;
}

// ---------------- scatter-add of 128-wide rows: agg[dst] += xw[src] ----------------
__global__ void k_scatter_add(const int* __restrict__ src, const int* __restrict__ dst,
                              const float* __restrict__ xw, float* __restrict__ agg, int E) {
  int gid = blockIdx.x*256 + threadIdx.x;
  int e = gid >> 5;
  if (e >= E) return;
  int c = (gid & 31) * 4;
  int s = src[e], d = dst[e];
  float4 v = *(const float4*)(xw + (size_t)s*CC + c);
  float* p = agg + (size_t)d*CC + c;
  atomicAdd(p+0, v.x); atomicAdd(p+1, v.y); atomicAdd(p+2, v.z); atomicAdd(p+3, v.w);
}

// ---------------- finalize graphconv: agg = agg * din^-1/2 + b ----------------
__global__ void k_finalize_gc(float* __restrict__ agg, const float* __restrict__ din,
                              const float* __restrict__ b) {
  int i = blockIdx.x*256 + threadIdx.x;
  if (i >= NN*CC) return;
  int row = i >> 7, col = i & 127;
  agg[i] = agg[i]*(1.0f/sqrtf(fmaxf(din[row],1.f))) + b[col];
}

// ---------------- el/er: per-node per-head attention logits ----------------
template<int H>
__global__ void k_elr(const float* __restrict__ f, const float* __restrict__ al,
                      const float* __restrict__ ar, float* __restrict__ el, float* __restrict__ er) {
  const int D = CC / H;
  int i = blockIdx.x*256 + threadIdx.x;   // over N*H
  if (i >= NN*H) return;
  int n = i / H, h = i % H;
  const float* fr = f + (size_t)n*CC + h*D;
  float a = 0.f, b = 0.f;
  for (int dd = 0; dd < D; ++dd) { float v = fr[dd]; a += v*al[h*D+dd]; b += v*ar[h*D+dd]; }
  el[i] = a; er[i] = b;
}

// ---------------- edge pass A: ex = exp(leaky(el[src]+er[dst])); s[dst] += ex ----------------
// NOTE: segment-max shift omitted — alpha = ex/sum is shift-invariant; |e| is O(1) here.
template<int H>
__global__ void k_edgeA(const int* __restrict__ src, const int* __restrict__ dst,
                        const float* __restrict__ el, const float* __restrict__ er,
                        float* __restrict__ exbuf, float* __restrict__ ssum) {
  int gid = blockIdx.x*256 + threadIdx.x;   // over EC*H
  if (gid >= ECE*H) return;
  int e = gid / H, h = gid % H;
  float v = el[src[e]*H+h] + er[dst[e]*H+h];
  v = (v >= 0.f) ? v : 0.2f*v;
  float ex = expf(v);
  exbuf[gid] = ex;
  atomicAdd(&ssum[dst[e]*H+h], ex);
}

// ---------------- edge pass B: out[dst] += alpha * f[src]; optional att_sum[src] += alpha ----
template<int H>
__global__ void k_edgeB(const int* __restrict__ src, const int* __restrict__ dst,
                        const float* __restrict__ exbuf, const float* __restrict__ ssum,
                        const float* __restrict__ f, float* __restrict__ out,
                        float* __restrict__ att) {
  int gid = blockIdx.x*256 + threadIdx.x;
  int e = gid >> 5;
  if (e >= ECE) return;
  int c = (gid & 31) * 4;
  int s = src[e], d = dst[e];
  int h = (c * H) >> 7;                  // c / (128/H)
  float alpha = exbuf[e*H+h] / ssum[d*H+h];
  float4 v = *(const float4*)(f + (size_t)s*CC + c);
  float* p = out + (size_t)d*CC + c;
  atomicAdd(p+0, alpha*v.x); atomicAdd(p+1, alpha*v.y);
  atomicAdd(p+2, alpha*v.z); atomicAdd(p+3, alpha*v.w);
  if (att != nullptr && c == 0) atomicAdd(&att[s], alpha);   // H==1 (layer 3) only
}

// ---------------- combine: t = maybe_leaky(hi + hc_agg + b_gat), in place ----------------
__global__ void k_combine(float* __restrict__ t, const float* __restrict__ bgat, int do_leaky) {
  int i = blockIdx.x*256 + threadIdx.x;
  if (i >= NN*CC) return;
  float v = t[i] + bgat[i & 127];
  if (do_leaky) v = (v >= 0.f) ? v : 0.2f*v;
  t[i] = v;
}

// ---------------- batchnorm stats: per-column sum / sumsq ----------------
__global__ void k_bn_stats(const float* __restrict__ t, float* __restrict__ cs, float* __restrict__ cq) {
  __shared__ float ls[256], lq[256];
  int col = threadIdx.x & 127, half = threadIdx.x >> 7;
  float s = 0.f, q = 0.f;
  for (int r = blockIdx.x*2 + half; r < NN; r += gridDim.x*2) {
    float v = t[(size_t)r*CC + col]; s += v; q += v*v;
  }
  ls[threadIdx.x] = s; lq[threadIdx.x] = q;
  __syncthreads();
  if (half == 0) {
    atomicAdd(&cs[col], ls[threadIdx.x] + ls[threadIdx.x+128]);
    atomicAdd(&cq[col], lq[threadIdx.x] + lq[threadIdx.x+128]);
  }
}

// ---------------- batchnorm apply ----------------
__global__ void k_bn_apply(const float* __restrict__ t, const float* __restrict__ cs,
                           const float* __restrict__ cq, const float* __restrict__ g,
                           const float* __restrict__ be, float* __restrict__ h) {
  int i = blockIdx.x*256 + threadIdx.x;
  if (i >= NN*CC) return;
  int col = i & 127;
  float mu = cs[col] * (1.f/NN);
  float var = cq[col] * (1.f/NN) - mu*mu;
  h[i] = g[col]*(t[i]-mu)*(1.0f/sqrtf(var + BNEPS)) + be[col];
}

// ---------------- pooling: frag[g] += h[n]*att_sum[n]; cnt[g] += 1 ----------------
__global__ void k_pool(const float* __restrict__ h, const float* __restrict__ att,
                       const int* __restrict__ gids, float* __restrict__ frag, float* __restrict__ cnt) {
  int gid = blockIdx.x*256 + threadIdx.x;
  int n = gid >> 5;
  if (n >= NN) return;
  int c = (gid & 31) * 4;
  int g = gids[n];
  float w = att[n];
  float4 v = *(const float4*)(h + (size_t)n*CC + c);
  float* p = frag + (size_t)g*CC + c;
  atomicAdd(p+0, v.x*w); atomicAdd(p+1, v.y*w);
  atomicAdd(p+2, v.z*w); atomicAdd(p+3, v.w*w);
  if (c == 0) atomicAdd(&cnt[g], 1.f);
}

__global__ void k_frag_div(float* __restrict__ frag, const float* __restrict__ cnt) {
  int i = blockIdx.x*256 + threadIdx.x;
  if (i >= GG*CC) return;
  frag[i] /= fmaxf(cnt[i >> 7], 1.f);
}

// ---------------- one full layer ----------------
template<int FIN, int H>
static void run_layer(const float* x, const float* Wgc, const float* bgc,
                      const float* Wgat, const float* al, const float* ar, const float* bgat,
                      const float* g, const float* be,
                      const int* isrc, const int* idst, const int* csrc, const int* cdst,
                      float* A, float* B, float* Hb,
                      float* el, float* er, float* ss, float* exb,
                      const float* dgo, const float* dgi, float* cs, float* cq,
                      float* att, int do_leaky, hipStream_t stream) {
  // GraphConv
  k_gemm<FIN><<<cdiv(NN,2), 256, 0, stream>>>(x, Wgc, dgo, A);
  hipMemsetAsync(B, 0, (size_t)NN*CC*sizeof(float), stream);
  k_scatter_add<<<cdiv((long)EIE*32,256), 256, 0, stream>>>(isrc, idst, A, B, EIE);
  k_finalize_gc<<<cdiv((long)NN*CC,256), 256, 0, stream>>>(B, dgi, bgc);
  // GAT (aggregates directly into B on top of finalized GraphConv)
  k_gemm<FIN><<<cdiv(NN,2), 256, 0, stream>>>(x, Wgat, nullptr, A);
  k_elr<H><<<cdiv((long)NN*H,256), 256, 0, stream>>>(A, al, ar, el, er);
  hipMemsetAsync(ss, 0, (size_t)NN*H*sizeof(float), stream);
  k_edgeA<H><<<cdiv((long)ECE*H,256), 256, 0, stream>>>(csrc, cdst, el, er, exb, ss);
  k_edgeB<H><<<cdiv((long)ECE*32,256), 256, 0, stream>>>(csrc, cdst, exb, ss, A, B, att);
  // combine + BN
  k_combine<<<cdiv((long)NN*CC,256), 256, 0, stream>>>(B, bgat, do_leaky);
  hipMemsetAsync(cs, 0, 2*CC*sizeof(float), stream);   // cs and cq contiguous
  k_bn_stats<<<512, 256, 0, stream>>>(B, cs, cq);
  k_bn_apply<<<cdiv((long)NN*CC,256), 256, 0, stream>>>(B, cs, cq, g, be, Hb);
}

extern "C" void kernel_launch(void* const* d_in, const int* in_sizes, int n_in,
                              void* d_out, int out_size, void* d_ws, size_t ws_size,
                              hipStream_t stream) {
  const float* feat  = (const float*)d_in[0];
  const int* isrc    = (const int*)d_in[1];
  const int* idst    = (const int*)d_in[2];
  const int* csrc    = (const int*)d_in[3];
  const int* cdst    = (const int*)d_in[4];
  const int* gids    = (const int*)d_in[5];
  const float* W_gc1 = (const float*)d_in[6];  const float* b_gc1 = (const float*)d_in[7];
  const float* W_gat1= (const float*)d_in[8];  const float* al1   = (const float*)d_in[9];
  const float* ar1   = (const float*)d_in[10]; const float* b_gat1= (const float*)d_in[11];
  const float* W_gc2 = (const float*)d_in[12]; const float* b_gc2 = (const float*)d_in[13];
  const float* W_gat2= (const float*)d_in[14]; const float* al2   = (const float*)d_in[15];
  const float* ar2   = (const float*)d_in[16]; const float* b_gat2= (const float*)d_in[17];
  const float* W_gc3 = (const float*)d_in[18]; const float* b_gc3 = (const float*)d_in[19];
  const float* W_gat3= (const float*)d_in[20]; const float* al3   = (const float*)d_in[21];
  const float* ar3   = (const float*)d_in[22]; const float* b_gat3= (const float*)d_in[23];
  const float* g1 = (const float*)d_in[24]; const float* be1 = (const float*)d_in[25];
  const float* g2 = (const float*)d_in[26]; const float* be2 = (const float*)d_in[27];
  const float* g3 = (const float*)d_in[28]; const float* be3 = (const float*)d_in[29];

  float* ws = (float*)d_ws;
  float* A   = ws;                 // N*128
  float* B   = A  + (size_t)NN*CC; // N*128
  float* Hb  = B  + (size_t)NN*CC; // N*128
  float* el  = Hb + (size_t)NN*CC; // N*4
  float* er  = el + (size_t)NN*4;  // N*4
  float* ss  = er + (size_t)NN*4;  // N*4
  float* exb = ss + (size_t)NN*4;  // EC*4
  float* dgo = exb + (size_t)ECE*4;// N
  float* dgi = dgo + NN;           // N
  float* cs  = dgi + NN;           // 128
  float* cq  = cs + CC;            // 128
  float* cnt = cq + CC;            // G

  float* frag = (float*)d_out;        // [G,128]
  float* att  = frag + (size_t)GG*CC; // [N]

  // degrees (inter edges) — dgo/dgi contiguous
  hipMemsetAsync(dgo, 0, 2*(size_t)NN*sizeof(float), stream);
  k_degrees<<<cdiv(EIE,256), 256, 0, stream>>>(isrc, idst, dgo, dgi);
  // outputs (att_sum accumulated by layer-3 edgeB; frag by pool)
  hipMemsetAsync(d_out, 0, (size_t)out_size*sizeof(float), stream);

  // layer 1: x = feat [N,512]
  run_layer<FDIM,4>(feat, W_gc1, b_gc1, W_gat1, al1, ar1, b_gat1, g1, be1,
                    isrc, idst, csrc, cdst, A, B, Hb, el, er, ss, exb,
                    dgo, dgi, cs, cq, nullptr, 1, stream);
  // layer 2: x = Hb [N,128]
  run_layer<CC,4>(Hb, W_gc2, b_gc2, W_gat2, al2, ar2, b_gat2, g2, be2,
                  isrc, idst, csrc, cdst, A, B, Hb, el, er, ss, exb,
                  dgo, dgi, cs, cq, nullptr, 1, stream);
  // layer 3: x = Hb, H=1, no leaky, att_sum accumulated
  run_layer<CC,1>(Hb, W_gc3, b_gc3, W_gat3, al3, ar3, b_gat3, g3, be3,
                  isrc, idst, csrc, cdst, A, B, Hb, el, er, ss, exb,
                  dgo, dgi, cs, cq, att, 0, stream);

  // pooling
  hipMemsetAsync(cnt, 0, GG*sizeof(float), stream);
  k_pool<<<cdiv((long)NN*32,256), 256, 0, stream>>>(Hb, att, gids, frag, cnt);
  k_frag_div<<<cdiv((long)GG*CC,256), 256, 0, stream>>>(frag, cnt);
}

// Round 2
// 6129.797 us; speedup vs baseline: 2.9211x; 2.9211x over previous
//
#include <hip/hip_runtime.h>
#include <math.h>

#define NN 100000
#define EIE 1600000
#define ECE 800000
#define GG 2000
#define FDIM 512
#define CC 128
#define BNEPS 1e-5f

static inline int cdiv(long a, long b){ return (int)((a+b-1)/b); }

// ---------------- degree counts: inter dst (CSR), cross dst (CSR), inter src (dout) ----
__global__ void k_count(const int* __restrict__ isrc, const int* __restrict__ idst,
                        const int* __restrict__ cdst,
                        int* __restrict__ deg_i, int* __restrict__ deg_c, int* __restrict__ dout) {
  int e = blockIdx.x*256 + threadIdx.x;
  if (e < EIE) { atomicAdd(&deg_i[idst[e]], 1); atomicAdd(&dout[isrc[e]], 1); }
  if (e < ECE) { atomicAdd(&deg_c[cdst[e]], 1); }
}

// ---------------- exclusive scan of the two degree arrays (one block each) ----------------
__global__ void k_scan2(const int* __restrict__ deg_i, int* __restrict__ offs_i,
                        const int* __restrict__ deg_c, int* __restrict__ offs_c) {
  const int* deg = blockIdx.x ? deg_c : deg_i;
  int* offs      = blockIdx.x ? offs_c : offs_i;
  __shared__ int sums[256];
  int t = threadIdx.x;
  const int chunk = (NN + 255) / 256;
  int lo = t*chunk, hi = min(lo + chunk, NN);
  int s = 0;
  for (int i = lo; i < hi; ++i) s += deg[i];
  sums[t] = s;
  __syncthreads();
  if (t == 0) { int run = 0; for (int i = 0; i < 256; ++i) { int v = sums[i]; sums[i] = run; run += v; } }
  __syncthreads();
  int run = sums[t];
  for (int i = lo; i < hi; ++i) { offs[i] = run; run += deg[i]; }
  if (t == 255) offs[NN] = run;
}

// ---------------- CSR fill: eid[offs[dst]+k] = src ----------------
__global__ void k_fill(const int* __restrict__ src, const int* __restrict__ dst,
                       const int* __restrict__ offs, int* __restrict__ cnt,
                       int* __restrict__ eid, int E) {
  int e = blockIdx.x*256 + threadIdx.x;
  if (e >= E) return;
  int d = dst[e];
  int p = offs[d] + atomicAdd(&cnt[d], 1);
  eid[p] = src[e];
}

// ---------------- GEMM: y[N,128] = x[N,FIN] @ W[FIN,128]; optional row scale dout^-1/2 ----
template<int FIN>
__global__ void k_gemm(const float* __restrict__ x, const float* __restrict__ W,
                       const int* __restrict__ rowdeg, float* __restrict__ y) {
  int col = threadIdx.x & 127;
  int row = blockIdx.x*2 + (threadIdx.x >> 7);
  if (row >= NN) return;
  const float* xr = x + (size_t)row*FIN;
  float acc = 0.f;
  #pragma unroll 2
  for (int k = 0; k < FIN; k += 4) {
    float4 xv = *(const float4*)(xr + k);
    acc += xv.x*W[(k+0)*CC+col];
    acc += xv.y*W[(k+1)*CC+col];
    acc += xv.z*W[(k+2)*CC+col];
    acc += xv.w*W[(k+3)*CC+col];
  }
  if (rowdeg) acc *= rsqrtf((float)max(rowdeg[row], 1));
  y[(size_t)row*CC+col] = acc;
}

// ---------------- GraphConv gather: out[d] = (sum_{e in CSR[d]} xw[src]) * din^-1/2 + b ----
__global__ void k_gc_gather(const float* __restrict__ xw, const int* __restrict__ offs,
                            const int* __restrict__ eid, const float* __restrict__ b,
                            float* __restrict__ out) {
  int lane = threadIdx.x & 31;
  int row = blockIdx.x*8 + (threadIdx.x >> 5);
  if (row >= NN) return;
  int lo = offs[row], hi = offs[row+1];
  float4 acc = {0.f,0.f,0.f,0.f};
  for (int j = lo; j < hi; ++j) {
    int s = eid[j];
    float4 v = *(const float4*)(xw + (size_t)s*CC + lane*4);
    acc.x += v.x; acc.y += v.y; acc.z += v.z; acc.w += v.w;
  }
  float sc = rsqrtf((float)max(hi - lo, 1));
  float4 bb = *(const float4*)(b + lane*4);
  float4 o;
  o.x = acc.x*sc + bb.x; o.y = acc.y*sc + bb.y;
  o.z = acc.z*sc + bb.z; o.w = acc.w*sc + bb.w;
  *(float4*)(out + (size_t)row*CC + lane*4) = o;
}

// ---------------- el/er: per-node per-head attention logits ----------------
template<int H>
__global__ void k_elr(const float* __restrict__ f, const float* __restrict__ al,
                      const float* __restrict__ ar, float* __restrict__ el, float* __restrict__ er) {
  const int D = CC / H;
  int i = blockIdx.x*256 + threadIdx.x;   // over N*H
  if (i >= NN*H) return;
  int n = i / H, h = i % H;
  const float* fr = f + (size_t)n*CC + h*D;
  float a = 0.f, b = 0.f;
  for (int dd = 0; dd < D; ++dd) { float v = fr[dd]; a += v*al[h*D+dd]; b += v*ar[h*D+dd]; }
  el[i] = a; er[i] = b;
}

// ---------------- GAT gather (two passes over in-edges), fused combine+bias+leaky --------
// NOTE: segment-max shift omitted — alpha = ex/sum is shift-invariant; |e| is O(1) here.
template<int H, bool ATT, bool LEAKY>
__global__ void k_gat_gather(const float* __restrict__ f, const int* __restrict__ offs,
                             const int* __restrict__ eid,
                             const float* __restrict__ el, const float* __restrict__ er,
                             const float* __restrict__ bgat, float* __restrict__ out,
                             float* __restrict__ att) {
  int lane = threadIdx.x & 31;
  int row = blockIdx.x*8 + (threadIdx.x >> 5);
  if (row >= NN) return;
  int h = (lane*4) / (CC/H);
  float erd = er[(size_t)row*H + h];
  int lo = offs[row], hi = offs[row+1];
  // pass 1: softmax denominator
  float denom = 0.f;
  for (int j = lo; j < hi; ++j) {
    int s = eid[j];
    float v = el[s*H+h] + erd;
    v = (v >= 0.f) ? v : 0.2f*v;
    denom += __expf(v);
  }
  float inv = (denom > 0.f) ? 1.0f/denom : 0.f;
  // pass 2: weighted aggregation
  float4 acc = {0.f,0.f,0.f,0.f};
  for (int j = lo; j < hi; ++j) {
    int s = eid[j];
    float v = el[s*H+h] + erd;
    v = (v >= 0.f) ? v : 0.2f*v;
    float alpha = __expf(v) * inv;
    float4 x = *(const float4*)(f + (size_t)s*CC + lane*4);
    acc.x += alpha*x.x; acc.y += alpha*x.y; acc.z += alpha*x.z; acc.w += alpha*x.w;
    if (ATT) { if (lane == 0) atomicAdd(&att[s], alpha); }   // H==1 only
  }
  float4 cur = *(const float4*)(out + (size_t)row*CC + lane*4);
  float4 bb = *(const float4*)(bgat + lane*4);
  float4 o;
  o.x = cur.x + acc.x + bb.x; o.y = cur.y + acc.y + bb.y;
  o.z = cur.z + acc.z + bb.z; o.w = cur.w + acc.w + bb.w;
  if (LEAKY) {
    o.x = (o.x >= 0.f) ? o.x : 0.2f*o.x; o.y = (o.y >= 0.f) ? o.y : 0.2f*o.y;
    o.z = (o.z >= 0.f) ? o.z : 0.2f*o.z; o.w = (o.w >= 0.f) ? o.w : 0.2f*o.w;
  }
  *(float4*)(out + (size_t)row*CC + lane*4) = o;
}

// ---------------- batchnorm stats: per-column sum / sumsq ----------------
__global__ void k_bn_stats(const float* __restrict__ t, float* __restrict__ cs, float* __restrict__ cq) {
  __shared__ float ls[256], lq[256];
  int col = threadIdx.x & 127, half = threadIdx.x >> 7;
  float s = 0.f, q = 0.f;
  for (int r = blockIdx.x*2 + half; r < NN; r += gridDim.x*2) {
    float v = t[(size_t)r*CC + col]; s += v; q += v*v;
  }
  ls[threadIdx.x] = s; lq[threadIdx.x] = q;
  __syncthreads();
  if (half == 0) {
    atomicAdd(&cs[col], ls[threadIdx.x] + ls[threadIdx.x+128]);
    atomicAdd(&cq[col], lq[threadIdx.x] + lq[threadIdx.x+128]);
  }
}

// ---------------- batchnorm apply ----------------
__global__ void k_bn_apply(const float* __restrict__ t, const float* __restrict__ cs,
                           const float* __restrict__ cq, const float* __restrict__ g,
                           const float* __restrict__ be, float* __restrict__ h) {
  int i = blockIdx.x*256 + threadIdx.x;
  if (i >= NN*CC) return;
  int col = i & 127;
  float mu = cs[col] * (1.f/NN);
  float var = cq[col] * (1.f/NN) - mu*mu;
  h[i] = g[col]*(t[i]-mu)*rsqrtf(var + BNEPS) + be[col];
}

// ---------------- pooling using sorted graph_ids: per-graph node range via binary search ----
__global__ void k_pool_csr(const float* __restrict__ h, const float* __restrict__ att,
                           const int* __restrict__ gids, float* __restrict__ frag) {
  int g = blockIdx.x;
  __shared__ int se[2];
  if (threadIdx.x < 2) {
    int target = g + threadIdx.x;
    int lo = 0, hi = NN;
    while (lo < hi) { int mid = (lo + hi) >> 1; if (gids[mid] < target) lo = mid + 1; else hi = mid; }
    se[threadIdx.x] = lo;
  }
  __syncthreads();
  int lo = se[0], hi = se[1];
  int col = threadIdx.x;
  float acc = 0.f;
  for (int n = lo; n < hi; ++n) acc += h[(size_t)n*CC + col] * att[n];
  frag[(size_t)g*CC + col] = acc / (float)max(hi - lo, 1);
}

// ---------------- one full layer ----------------
template<int FIN, int H, bool ATT, bool LEAKY>
static void run_layer(const float* x, const float* Wgc, const float* bgc,
                      const float* Wgat, const float* al, const float* ar, const float* bgat,
                      const float* g, const float* be,
                      const int* offs_i, const int* eid_i, const int* offs_c, const int* eid_c,
                      const int* dout,
                      float* A, float* B, float* Hb, float* el, float* er,
                      float* cs, float* cq, float* att, hipStream_t stream) {
  k_gemm<FIN><<<cdiv(NN,2), 256, 0, stream>>>(x, Wgc, dout, A);          // A = xW * dout^-1/2
  k_gc_gather<<<cdiv(NN,8), 256, 0, stream>>>(A, offs_i, eid_i, bgc, B); // B = agg*din^-1/2 + b
  k_gemm<FIN><<<cdiv(NN,2), 256, 0, stream>>>(x, Wgat, nullptr, A);      // A = f
  k_elr<H><<<cdiv((long)NN*H,256), 256, 0, stream>>>(A, al, ar, el, er);
  k_gat_gather<H,ATT,LEAKY><<<cdiv(NN,8), 256, 0, stream>>>(A, offs_c, eid_c, el, er, bgat, B, att);
  hipMemsetAsync(cs, 0, 2*CC*sizeof(float), stream);                     // cs,cq contiguous
  k_bn_stats<<<512, 256, 0, stream>>>(B, cs, cq);
  k_bn_apply<<<cdiv((long)NN*CC,256), 256, 0, stream>>>(B, cs, cq, g, be, Hb);
}

extern "C" void kernel_launch(void* const* d_in, const int* in_sizes, int n_in,
                              void* d_out, int out_size, void* d_ws, size_t ws_size,
                              hipStream_t stream) {
  const float* feat  = (const float*)d_in[0];
  const int* isrc    = (const int*)d_in[1];
  const int* idst    = (const int*)d_in[2];
  const int* csrc    = (const int*)d_in[3];
  const int* cdst    = (const int*)d_in[4];
  const int* gids    = (const int*)d_in[5];
  const float* W_gc1 = (const float*)d_in[6];  const float* b_gc1 = (const float*)d_in[7];
  const float* W_gat1= (const float*)d_in[8];  const float* al1   = (const float*)d_in[9];
  const float* ar1   = (const float*)d_in[10]; const float* b_gat1= (const float*)d_in[11];
  const float* W_gc2 = (const float*)d_in[12]; const float* b_gc2 = (const float*)d_in[13];
  const float* W_gat2= (const float*)d_in[14]; const float* al2   = (const float*)d_in[15];
  const float* ar2   = (const float*)d_in[16]; const float* b_gat2= (const float*)d_in[17];
  const float* W_gc3 = (const float*)d_in[18]; const float* b_gc3 = (const float*)d_in[19];
  const float* W_gat3= (const float*)d_in[20]; const float* al3   = (const float*)d_in[21];
  const float* ar3   = (const float*)d_in[22]; const float* b_gat3= (const float*)d_in[23];
  const float* g1 = (const float*)d_in[24]; const float* be1 = (const float*)d_in[25];
  const float* g2 = (const float*)d_in[26]; const float* be2 = (const float*)d_in[27];
  const float* g3 = (const float*)d_in[28]; const float* be3 = (const float*)d_in[29];

  const size_t NC = (size_t)NN*CC;
  float* A  = (float*)d_ws;
  float* B  = A  + NC;
  float* Hb = B  + NC;
  float* el = Hb + NC;            // N*4
  float* er = el + (size_t)NN*4;  // N*4
  float* cs = er + (size_t)NN*4;  // 128
  float* cq = cs + CC;            // 128
  int* offs_i = (int*)(cq + CC);  // N+1
  int* offs_c = offs_i + (NN+1);  // N+1
  int* deg_i  = offs_c + (NN+1);  // N   (deg_i..dout contiguous: 5N, one memset)
  int* deg_c  = deg_i + NN;       // N
  int* cnt_i  = deg_c + NN;       // N
  int* cnt_c  = cnt_i + NN;       // N
  int* dout   = cnt_c + NN;       // N
  int* eid_i  = dout + NN;        // EI
  int* eid_c  = eid_i + EIE;      // EC

  float* frag = (float*)d_out;        // [G,128]
  float* att  = frag + (size_t)GG*CC; // [N]

  // ---- build CSR (per call; inputs re-poisoned each launch) ----
  hipMemsetAsync(deg_i, 0, 5*(size_t)NN*sizeof(int), stream);
  hipMemsetAsync(att, 0, (size_t)NN*sizeof(float), stream);
  k_count<<<cdiv(EIE,256), 256, 0, stream>>>(isrc, idst, cdst, deg_i, deg_c, dout);
  k_scan2<<<2, 256, 0, stream>>>(deg_i, offs_i, deg_c, offs_c);
  k_fill<<<cdiv(EIE,256), 256, 0, stream>>>(isrc, idst, offs_i, cnt_i, eid_i, EIE);
  k_fill<<<cdiv(ECE,256), 256, 0, stream>>>(csrc, cdst, offs_c, cnt_c, eid_c, ECE);

  // ---- layers ----
  run_layer<FDIM,4,false,true>(feat, W_gc1, b_gc1, W_gat1, al1, ar1, b_gat1, g1, be1,
                               offs_i, eid_i, offs_c, eid_c, dout,
                               A, B, Hb, el, er, cs, cq, nullptr, stream);
  run_layer<CC,4,false,true>(Hb, W_gc2, b_gc2, W_gat2, al2, ar2, b_gat2, g2, be2,
                             offs_i, eid_i, offs_c, eid_c, dout,
                             A, B, Hb, el, er, cs, cq, nullptr, stream);
  run_layer<CC,1,true,false>(Hb, W_gc3, b_gc3, W_gat3, al3, ar3, b_gat3, g3, be3,
                             offs_i, eid_i, offs_c, eid_c, dout,
                             A, B, Hb, el, er, cs, cq, att, stream);

  // ---- pooling (graph_ids sorted) ----
  k_pool_csr<<<GG, 128, 0, stream>>>(Hb, att, gids, frag);
}

// Round 3
// 2341.284 us; speedup vs baseline: 7.6478x; 2.6181x over previous
//
#include <hip/hip_runtime.h>
#include <math.h>

#define NN 100000
#define EIE 1600000
#define ECE 800000
#define GG 2000
#define FDIM 512
#define CC 128
#define BNEPS 1e-5f

static inline int cdiv(long a, long b){ return (int)((a+b-1)/b); }

// ---------------- degree counts: inter dst (CSR), cross dst (CSR), inter src (dout) ----
__global__ void k_count(const int* __restrict__ isrc, const int* __restrict__ idst,
                        const int* __restrict__ cdst,
                        int* __restrict__ deg_i, int* __restrict__ deg_c, int* __restrict__ dout) {
  int e = blockIdx.x*256 + threadIdx.x;
  if (e < EIE) { atomicAdd(&deg_i[idst[e]], 1); atomicAdd(&dout[isrc[e]], 1); }
  if (e < ECE) { atomicAdd(&deg_c[cdst[e]], 1); }
}

// ---------------- exclusive scan of the two degree arrays (one block each) ----------------
__global__ void k_scan2(const int* __restrict__ deg_i, int* __restrict__ offs_i,
                        const int* __restrict__ deg_c, int* __restrict__ offs_c) {
  const int* deg = blockIdx.x ? deg_c : deg_i;
  int* offs      = blockIdx.x ? offs_c : offs_i;
  __shared__ int sums[256];
  int t = threadIdx.x;
  const int chunk = (NN + 255) / 256;
  int lo = t*chunk, hi = min(lo + chunk, NN);
  int s = 0;
  for (int i = lo; i < hi; ++i) s += deg[i];
  sums[t] = s;
  __syncthreads();
  if (t == 0) { int run = 0; for (int i = 0; i < 256; ++i) { int v = sums[i]; sums[i] = run; run += v; } }
  __syncthreads();
  int run = sums[t];
  for (int i = lo; i < hi; ++i) { offs[i] = run; run += deg[i]; }
  if (t == 255) offs[NN] = run;
}

// ---------------- CSR fill: eid[offs[dst]+k] = src ----------------
__global__ void k_fill(const int* __restrict__ src, const int* __restrict__ dst,
                       const int* __restrict__ offs, int* __restrict__ cnt,
                       int* __restrict__ eid, int E) {
  int e = blockIdx.x*256 + threadIdx.x;
  if (e >= E) return;
  int d = dst[e];
  int p = offs[d] + atomicAdd(&cnt[d], 1);
  eid[p] = src[e];
}

// ---------------- tiled GEMM: y[N,128] = x[N,FIN] @ W[FIN,128]; optional dout^-1/2 scale ----
// 128x128 output tile per block, K-tile=32 in LDS, 8x8 register acc per thread.
template<int FIN>
__global__ __launch_bounds__(256)
void k_gemm_t(const float* __restrict__ x, const float* __restrict__ W,
              const int* __restrict__ rowdeg, float* __restrict__ y) {
  const int KT = 32;
  __shared__ float sW[KT][CC];        // 16 KB
  __shared__ float sX[KT][132];       // x transposed, padded; ~16.9 KB
  int tid = threadIdx.x;
  int tc = tid & 15;                  // col group: 16 groups x 8 cols
  int tr = tid >> 4;                  // row group: 16 groups x 8 rows
  int row0 = blockIdx.x * 128;
  float acc[8][8];
  #pragma unroll
  for (int j = 0; j < 8; ++j)
    #pragma unroll
    for (int c = 0; c < 8; ++c) acc[j][c] = 0.f;

  for (int k0 = 0; k0 < FIN; k0 += KT) {
    // W tile: 32 rows x 128 cols = 1024 float4, 4 per thread
    #pragma unroll
    for (int i = 0; i < 4; ++i) {
      int idx = tid + i*256;
      int r = idx >> 5, cv = idx & 31;
      *(float4*)&sW[r][cv*4] = *(const float4*)&W[(size_t)(k0+r)*CC + cv*4];
    }
    // x tile: 128 rows x 32 k = 1024 float4, 4 per thread, transposed into sX
    #pragma unroll
    for (int i = 0; i < 4; ++i) {
      int idx = tid + i*256;
      int m = idx >> 3, kv = idx & 7;
      int gr = row0 + m; if (gr >= NN) gr = NN - 1;
      float4 v = *(const float4*)&x[(size_t)gr*FIN + k0 + kv*4];
      sX[kv*4+0][m] = v.x; sX[kv*4+1][m] = v.y;
      sX[kv*4+2][m] = v.z; sX[kv*4+3][m] = v.w;
    }
    __syncthreads();
    #pragma unroll 8
    for (int kk = 0; kk < KT; ++kk) {
      float4 wa = *(float4*)&sW[kk][tc*8];
      float4 wb = *(float4*)&sW[kk][tc*8+4];
      float4 xa = *(float4*)&sX[kk][tr*8];
      float4 xb = *(float4*)&sX[kk][tr*8+4];
      float wr[8] = {wa.x,wa.y,wa.z,wa.w,wb.x,wb.y,wb.z,wb.w};
      float xr[8] = {xa.x,xa.y,xa.z,xa.w,xb.x,xb.y,xb.z,xb.w};
      #pragma unroll
      for (int j = 0; j < 8; ++j)
        #pragma unroll
        for (int c = 0; c < 8; ++c)
          acc[j][c] += xr[j]*wr[c];
    }
    __syncthreads();
  }
  #pragma unroll
  for (int j = 0; j < 8; ++j) {
    int row = row0 + tr*8 + j;
    if (row >= NN) break;
    float sc = rowdeg ? rsqrtf((float)max(rowdeg[row], 1)) : 1.f;
    float4 o0 = {acc[j][0]*sc, acc[j][1]*sc, acc[j][2]*sc, acc[j][3]*sc};
    float4 o1 = {acc[j][4]*sc, acc[j][5]*sc, acc[j][6]*sc, acc[j][7]*sc};
    *(float4*)&y[(size_t)row*CC + tc*8]     = o0;
    *(float4*)&y[(size_t)row*CC + tc*8 + 4] = o1;
  }
}

// ---------------- GraphConv gather: out[d] = (sum_{e in CSR[d]} xw[src]) * din^-1/2 + b ----
__global__ void k_gc_gather(const float* __restrict__ xw, const int* __restrict__ offs,
                            const int* __restrict__ eid, const float* __restrict__ b,
                            float* __restrict__ out) {
  int lane = threadIdx.x & 31;
  int row = blockIdx.x*8 + (threadIdx.x >> 5);
  if (row >= NN) return;
  int lo = offs[row], hi = offs[row+1];
  float4 acc = {0.f,0.f,0.f,0.f};
  for (int j = lo; j < hi; ++j) {
    int s = eid[j];
    float4 v = *(const float4*)(xw + (size_t)s*CC + lane*4);
    acc.x += v.x; acc.y += v.y; acc.z += v.z; acc.w += v.w;
  }
  float sc = rsqrtf((float)max(hi - lo, 1));
  float4 bb = *(const float4*)(b + lane*4);
  float4 o;
  o.x = acc.x*sc + bb.x; o.y = acc.y*sc + bb.y;
  o.z = acc.z*sc + bb.z; o.w = acc.w*sc + bb.w;
  *(float4*)(out + (size_t)row*CC + lane*4) = o;
}

// ---------------- el/er: per-node per-head attention logits ----------------
template<int H>
__global__ void k_elr(const float* __restrict__ f, const float* __restrict__ al,
                      const float* __restrict__ ar, float* __restrict__ el, float* __restrict__ er) {
  const int D = CC / H;
  int i = blockIdx.x*256 + threadIdx.x;   // over N*H
  if (i >= NN*H) return;
  int n = i / H, h = i % H;
  const float* fr = f + (size_t)n*CC + h*D;
  float a = 0.f, b = 0.f;
  for (int dd = 0; dd < D; ++dd) { float v = fr[dd]; a += v*al[h*D+dd]; b += v*ar[h*D+dd]; }
  el[i] = a; er[i] = b;
}

// ---------------- GAT gather (two passes over in-edges), fused combine+bias+leaky --------
// NOTE: segment-max shift omitted — alpha = ex/sum is shift-invariant; |e| is O(1) here.
template<int H, bool ATT, bool LEAKY>
__global__ void k_gat_gather(const float* __restrict__ f, const int* __restrict__ offs,
                             const int* __restrict__ eid,
                             const float* __restrict__ el, const float* __restrict__ er,
                             const float* __restrict__ bgat, float* __restrict__ out,
                             float* __restrict__ att) {
  int lane = threadIdx.x & 31;
  int row = blockIdx.x*8 + (threadIdx.x >> 5);
  if (row >= NN) return;
  int h = (lane*4) / (CC/H);
  float erd = er[(size_t)row*H + h];
  int lo = offs[row], hi = offs[row+1];
  float denom = 0.f;
  for (int j = lo; j < hi; ++j) {
    int s = eid[j];
    float v = el[s*H+h] + erd;
    v = (v >= 0.f) ? v : 0.2f*v;
    denom += __expf(v);
  }
  float inv = (denom > 0.f) ? 1.0f/denom : 0.f;
  float4 acc = {0.f,0.f,0.f,0.f};
  for (int j = lo; j < hi; ++j) {
    int s = eid[j];
    float v = el[s*H+h] + erd;
    v = (v >= 0.f) ? v : 0.2f*v;
    float alpha = __expf(v) * inv;
    float4 x = *(const float4*)(f + (size_t)s*CC + lane*4);
    acc.x += alpha*x.x; acc.y += alpha*x.y; acc.z += alpha*x.z; acc.w += alpha*x.w;
    if (ATT) { if (lane == 0) atomicAdd(&att[s], alpha); }   // H==1 only
  }
  float4 cur = *(const float4*)(out + (size_t)row*CC + lane*4);
  float4 bb = *(const float4*)(bgat + lane*4);
  float4 o;
  o.x = cur.x + acc.x + bb.x; o.y = cur.y + acc.y + bb.y;
  o.z = cur.z + acc.z + bb.z; o.w = cur.w + acc.w + bb.w;
  if (LEAKY) {
    o.x = (o.x >= 0.f) ? o.x : 0.2f*o.x; o.y = (o.y >= 0.f) ? o.y : 0.2f*o.y;
    o.z = (o.z >= 0.f) ? o.z : 0.2f*o.z; o.w = (o.w >= 0.f) ? o.w : 0.2f*o.w;
  }
  *(float4*)(out + (size_t)row*CC + lane*4) = o;
}

// ---------------- batchnorm stats: per-column sum / sumsq ----------------
__global__ void k_bn_stats(const float* __restrict__ t, float* __restrict__ cs, float* __restrict__ cq) {
  __shared__ float ls[256], lq[256];
  int col = threadIdx.x & 127, half = threadIdx.x >> 7;
  float s = 0.f, q = 0.f;
  for (int r = blockIdx.x*2 + half; r < NN; r += gridDim.x*2) {
    float v = t[(size_t)r*CC + col]; s += v; q += v*v;
  }
  ls[threadIdx.x] = s; lq[threadIdx.x] = q;
  __syncthreads();
  if (half == 0) {
    atomicAdd(&cs[col], ls[threadIdx.x] + ls[threadIdx.x+128]);
    atomicAdd(&cq[col], lq[threadIdx.x] + lq[threadIdx.x+128]);
  }
}

// ---------------- batchnorm apply ----------------
__global__ void k_bn_apply(const float* __restrict__ t, const float* __restrict__ cs,
                           const float* __restrict__ cq, const float* __restrict__ g,
                           const float* __restrict__ be, float* __restrict__ h) {
  int i = blockIdx.x*256 + threadIdx.x;
  if (i >= NN*CC) return;
  int col = i & 127;
  float mu = cs[col] * (1.f/NN);
  float var = cq[col] * (1.f/NN) - mu*mu;
  h[i] = g[col]*(t[i]-mu)*rsqrtf(var + BNEPS) + be[col];
}

// ---------------- pooling using sorted graph_ids: per-graph node range via binary search ----
__global__ void k_pool_csr(const float* __restrict__ h, const float* __restrict__ att,
                           const int* __restrict__ gids, float* __restrict__ frag) {
  int g = blockIdx.x;
  __shared__ int se[2];
  if (threadIdx.x < 2) {
    int target = g + threadIdx.x;
    int lo = 0, hi = NN;
    while (lo < hi) { int mid = (lo + hi) >> 1; if (gids[mid] < target) lo = mid + 1; else hi = mid; }
    se[threadIdx.x] = lo;
  }
  __syncthreads();
  int lo = se[0], hi = se[1];
  int col = threadIdx.x;
  float acc = 0.f;
  for (int n = lo; n < hi; ++n) acc += h[(size_t)n*CC + col] * att[n];
  frag[(size_t)g*CC + col] = acc / (float)max(hi - lo, 1);
}

// ---------------- one full layer ----------------
template<int FIN, int H, bool ATT, bool LEAKY>
static void run_layer(const float* x, const float* Wgc, const float* bgc,
                      const float* Wgat, const float* al, const float* ar, const float* bgat,
                      const float* g, const float* be,
                      const int* offs_i, const int* eid_i, const int* offs_c, const int* eid_c,
                      const int* dout,
                      float* A, float* B, float* Hb, float* el, float* er,
                      float* cs, float* cq, float* att, hipStream_t stream) {
  k_gemm_t<FIN><<<cdiv(NN,128), 256, 0, stream>>>(x, Wgc, dout, A);       // A = xW * dout^-1/2
  k_gc_gather<<<cdiv(NN,8), 256, 0, stream>>>(A, offs_i, eid_i, bgc, B);  // B = agg*din^-1/2 + b
  k_gemm_t<FIN><<<cdiv(NN,128), 256, 0, stream>>>(x, Wgat, nullptr, A);   // A = f
  k_elr<H><<<cdiv((long)NN*H,256), 256, 0, stream>>>(A, al, ar, el, er);
  k_gat_gather<H,ATT,LEAKY><<<cdiv(NN,8), 256, 0, stream>>>(A, offs_c, eid_c, el, er, bgat, B, att);
  hipMemsetAsync(cs, 0, 2*CC*sizeof(float), stream);                      // cs,cq contiguous
  k_bn_stats<<<512, 256, 0, stream>>>(B, cs, cq);
  k_bn_apply<<<cdiv((long)NN*CC,256), 256, 0, stream>>>(B, cs, cq, g, be, Hb);
}

extern "C" void kernel_launch(void* const* d_in, const int* in_sizes, int n_in,
                              void* d_out, int out_size, void* d_ws, size_t ws_size,
                              hipStream_t stream) {
  const float* feat  = (const float*)d_in[0];
  const int* isrc    = (const int*)d_in[1];
  const int* idst    = (const int*)d_in[2];
  const int* csrc    = (const int*)d_in[3];
  const int* cdst    = (const int*)d_in[4];
  const int* gids    = (const int*)d_in[5];
  const float* W_gc1 = (const float*)d_in[6];  const float* b_gc1 = (const float*)d_in[7];
  const float* W_gat1= (const float*)d_in[8];  const float* al1   = (const float*)d_in[9];
  const float* ar1   = (const float*)d_in[10]; const float* b_gat1= (const float*)d_in[11];
  const float* W_gc2 = (const float*)d_in[12]; const float* b_gc2 = (const float*)d_in[13];
  const float* W_gat2= (const float*)d_in[14]; const float* al2   = (const float*)d_in[15];
  const float* ar2   = (const float*)d_in[16]; const float* b_gat2= (const float*)d_in[17];
  const float* W_gc3 = (const float*)d_in[18]; const float* b_gc3 = (const float*)d_in[19];
  const float* W_gat3= (const float*)d_in[20]; const float* al3   = (const float*)d_in[21];
  const float* ar3   = (const float*)d_in[22]; const float* b_gat3= (const float*)d_in[23];
  const float* g1 = (const float*)d_in[24]; const float* be1 = (const float*)d_in[25];
  const float* g2 = (const float*)d_in[26]; const float* be2 = (const float*)d_in[27];
  const float* g3 = (const float*)d_in[28]; const float* be3 = (const float*)d_in[29];

  const size_t NC = (size_t)NN*CC;
  float* A  = (float*)d_ws;
  float* B  = A  + NC;
  float* Hb = B  + NC;
  float* el = Hb + NC;            // N*4
  float* er = el + (size_t)NN*4;  // N*4
  float* cs = er + (size_t)NN*4;  // 128
  float* cq = cs + CC;            // 128
  int* offs_i = (int*)(cq + CC);  // N+1
  int* offs_c = offs_i + (NN+1);  // N+1
  int* deg_i  = offs_c + (NN+1);  // N   (deg_i..dout contiguous: 5N, one memset)
  int* deg_c  = deg_i + NN;       // N
  int* cnt_i  = deg_c + NN;       // N
  int* cnt_c  = cnt_i + NN;       // N
  int* dout   = cnt_c + NN;       // N
  int* eid_i  = dout + NN;        // EI
  int* eid_c  = eid_i + EIE;      // EC

  float* frag = (float*)d_out;        // [G,128]
  float* att  = frag + (size_t)GG*CC; // [N]

  // ---- build CSR (per call; inputs re-poisoned each launch) ----
  hipMemsetAsync(deg_i, 0, 5*(size_t)NN*sizeof(int), stream);
  hipMemsetAsync(att, 0, (size_t)NN*sizeof(float), stream);
  k_count<<<cdiv(EIE,256), 256, 0, stream>>>(isrc, idst, cdst, deg_i, deg_c, dout);
  k_scan2<<<2, 256, 0, stream>>>(deg_i, offs_i, deg_c, offs_c);
  k_fill<<<cdiv(EIE,256), 256, 0, stream>>>(isrc, idst, offs_i, cnt_i, eid_i, EIE);
  k_fill<<<cdiv(ECE,256), 256, 0, stream>>>(csrc, cdst, offs_c, cnt_c, eid_c, ECE);

  // ---- layers ----
  run_layer<FDIM,4,false,true>(feat, W_gc1, b_gc1, W_gat1, al1, ar1, b_gat1, g1, be1,
                               offs_i, eid_i, offs_c, eid_c, dout,
                               A, B, Hb, el, er, cs, cq, nullptr, stream);
  run_layer<CC,4,false,true>(Hb, W_gc2, b_gc2, W_gat2, al2, ar2, b_gat2, g2, be2,
                             offs_i, eid_i, offs_c, eid_c, dout,
                             A, B, Hb, el, er, cs, cq, nullptr, stream);
  run_layer<CC,1,true,false>(Hb, W_gc3, b_gc3, W_gat3, al3, ar3, b_gat3, g3, be3,
                             offs_i, eid_i, offs_c, eid_c, dout,
                             A, B, Hb, el, er, cs, cq, att, stream);

  // ---- pooling (graph_ids sorted) ----
  k_pool_csr<<<GG, 128, 0, stream>>>(Hb, att, gids, frag);
}

// Round 4
// 2017.611 us; speedup vs baseline: 8.8747x; 1.1604x over previous
//
#include <hip/hip_runtime.h>
#include <math.h>

#define NN 100000
#define EIE 1600000
#define ECE 800000
#define GG 2000
#define FDIM 512
#define CC 128
#define BNEPS 1e-5f

static inline int cdiv(long a, long b){ return (int)((a+b-1)/b); }

typedef __attribute__((ext_vector_type(8))) short short8;
typedef __attribute__((ext_vector_type(4))) float f32x4;

__device__ __forceinline__ unsigned short f2bf(float f){
  unsigned u = __float_as_uint(f);
  u += 0x7fffu + ((u >> 16) & 1u);
  return (unsigned short)(u >> 16);
}
__device__ __forceinline__ float bf2f(unsigned short h){
  return __uint_as_float(((unsigned)h) << 16);
}

// ---------------- degree counts: inter dst (CSR), cross dst (CSR), inter src (dout) ----
__global__ void k_count(const int* __restrict__ isrc, const int* __restrict__ idst,
                        const int* __restrict__ cdst,
                        int* __restrict__ deg_i, int* __restrict__ deg_c, int* __restrict__ dout) {
  int e = blockIdx.x*256 + threadIdx.x;
  if (e < EIE) { atomicAdd(&deg_i[idst[e]], 1); atomicAdd(&dout[isrc[e]], 1); }
  if (e < ECE) { atomicAdd(&deg_c[cdst[e]], 1); }
}

// ---------------- exclusive scan of the two degree arrays (one block each) ----------------
__global__ void k_scan2(const int* __restrict__ deg_i, int* __restrict__ offs_i,
                        const int* __restrict__ deg_c, int* __restrict__ offs_c) {
  const int* deg = blockIdx.x ? deg_c : deg_i;
  int* offs      = blockIdx.x ? offs_c : offs_i;
  __shared__ int sums[256];
  int t = threadIdx.x;
  const int chunk = (NN + 255) / 256;
  int lo = t*chunk, hi = min(lo + chunk, NN);
  int s = 0;
  for (int i = lo; i < hi; ++i) s += deg[i];
  sums[t] = s;
  __syncthreads();
  if (t == 0) { int run = 0; for (int i = 0; i < 256; ++i) { int v = sums[i]; sums[i] = run; run += v; } }
  __syncthreads();
  int run = sums[t];
  for (int i = lo; i < hi; ++i) { offs[i] = run; run += deg[i]; }
  if (t == 255) offs[NN] = run;
}

// ---------------- CSR fill: eid[offs[dst]+k] = src ----------------
__global__ void k_fill(const int* __restrict__ src, const int* __restrict__ dst,
                       const int* __restrict__ offs, int* __restrict__ cnt,
                       int* __restrict__ eid, int E) {
  int e = blockIdx.x*256 + threadIdx.x;
  if (e >= E) return;
  int d = dst[e];
  int p = offs[d] + atomicAdd(&cnt[d], 1);
  eid[p] = src[e];
}

// ---------------- pack W: [FIN][128]x2 fp32 -> transposed bf16 hi/lo [256][FIN] ----------
template<int FIN>
__global__ void k_pack_w(const float* __restrict__ W1, const float* __restrict__ W2,
                         unsigned short* __restrict__ Wth, unsigned short* __restrict__ Wtl) {
  int tid = blockIdx.x*256 + threadIdx.x;
  if (tid >= 256*FIN) return;
  int n = tid / FIN, k = tid % FIN;
  float v = (n < 128) ? W1[(size_t)k*128 + n] : W2[(size_t)k*128 + (n-128)];
  unsigned short h = f2bf(v);
  Wth[tid] = h;
  Wtl[tid] = f2bf(v - bf2f(h));
}

// ---------------- dual MFMA GEMM (bf16x3): Y1 = (x@W1)*dout^-1/2, Y2 = x@W2 ----------
// 128 rows x 256 cols per block; 4 waves in 2x2; 16x16x32 bf16 MFMA; fp32-grade accuracy
// via xh*Wh + xh*Wl + xl*Wh. x converted fp32->bf16 h/l on the fly during LDS staging.
template<int FIN>
__global__ __launch_bounds__(256)
void k_gemm2(const float* __restrict__ x, const unsigned short* __restrict__ Bh,
             const unsigned short* __restrict__ Bl, const int* __restrict__ rowdeg,
             float* __restrict__ Y1, float* __restrict__ Y2) {
  __shared__ unsigned short sAh[128][32];   // 8 KB
  __shared__ unsigned short sAl[128][32];   // 8 KB
  __shared__ unsigned short sBh[256][32];   // 16 KB
  __shared__ unsigned short sBl[256][32];   // 16 KB
  int tid = threadIdx.x;
  int row0 = blockIdx.x*128;
  int lane = tid & 63, wid = tid >> 6;
  int wm = wid >> 1, wn = wid & 1;          // wave grid 2x2 over (128 rows, 256 cols)
  int l15 = lane & 15, quad = lane >> 4;

  f32x4 acc[4][8];
  #pragma unroll
  for (int mt = 0; mt < 4; ++mt)
    #pragma unroll
    for (int nt = 0; nt < 8; ++nt) acc[mt][nt] = (f32x4){0.f,0.f,0.f,0.f};

  for (int k0 = 0; k0 < FIN; k0 += 32) {
    // stage A: 128 rows x 32 k fp32 -> bf16 h/l (1024 float4, 4/thread)
    #pragma unroll
    for (int i = 0; i < 4; ++i) {
      int idx = tid + i*256;
      int r = idx >> 3, c = idx & 7;
      int gr = row0 + r; if (gr > NN-1) gr = NN-1;
      float4 v = *(const float4*)(x + (size_t)gr*FIN + k0 + c*4);
      ushort4 hh, ll;
      hh.x = f2bf(v.x); hh.y = f2bf(v.y); hh.z = f2bf(v.z); hh.w = f2bf(v.w);
      ll.x = f2bf(v.x - bf2f(hh.x)); ll.y = f2bf(v.y - bf2f(hh.y));
      ll.z = f2bf(v.z - bf2f(hh.z)); ll.w = f2bf(v.w - bf2f(hh.w));
      *(ushort4*)&sAh[r][c*4] = hh;
      *(ushort4*)&sAl[r][c*4] = ll;
    }
    // stage B: 256 n-rows x 32 k bf16 h/l (1024 x 16B, 4/thread each)
    #pragma unroll
    for (int i = 0; i < 4; ++i) {
      int idx = tid + i*256;
      int n = idx >> 2, c = idx & 3;
      *(float4*)&sBh[n][c*8] = *(const float4*)(Bh + (size_t)n*FIN + k0 + c*8);
      *(float4*)&sBl[n][c*8] = *(const float4*)(Bl + (size_t)n*FIN + k0 + c*8);
    }
    __syncthreads();
    short8 ah[4], al2[4];
    #pragma unroll
    for (int mt = 0; mt < 4; ++mt) {
      ah[mt]  = *(const short8*)&sAh[wm*64 + mt*16 + l15][quad*8];
      al2[mt] = *(const short8*)&sAl[wm*64 + mt*16 + l15][quad*8];
    }
    #pragma unroll
    for (int nt = 0; nt < 8; ++nt) {
      short8 bh = *(const short8*)&sBh[wn*128 + nt*16 + l15][quad*8];
      short8 bl = *(const short8*)&sBl[wn*128 + nt*16 + l15][quad*8];
      #pragma unroll
      for (int mt = 0; mt < 4; ++mt) {
        acc[mt][nt] = __builtin_amdgcn_mfma_f32_16x16x32_bf16(ah[mt],  bh, acc[mt][nt], 0,0,0);
        acc[mt][nt] = __builtin_amdgcn_mfma_f32_16x16x32_bf16(ah[mt],  bl, acc[mt][nt], 0,0,0);
        acc[mt][nt] = __builtin_amdgcn_mfma_f32_16x16x32_bf16(al2[mt], bh, acc[mt][nt], 0,0,0);
      }
    }
    __syncthreads();
  }
  // epilogue: D layout col=lane&15, row=quad*4+reg
  float* Y = wn ? Y2 : Y1;
  #pragma unroll
  for (int mt = 0; mt < 4; ++mt) {
    #pragma unroll
    for (int r = 0; r < 4; ++r) {
      int row = row0 + wm*64 + mt*16 + quad*4 + r;
      if (row >= NN) continue;
      float sc = wn ? 1.0f : rsqrtf((float)max(rowdeg[row], 1));
      #pragma unroll
      for (int nt = 0; nt < 8; ++nt)
        Y[(size_t)row*CC + nt*16 + l15] = acc[mt][nt][r]*sc;
    }
  }
}

// ---------------- GraphConv gather: out[d] = (sum_{e in CSR[d]} xw[src]) * din^-1/2 + b ----
__global__ void k_gc_gather(const float* __restrict__ xw, const int* __restrict__ offs,
                            const int* __restrict__ eid, const float* __restrict__ b,
                            float* __restrict__ out) {
  int lane = threadIdx.x & 31;
  int row = blockIdx.x*8 + (threadIdx.x >> 5);
  if (row >= NN) return;
  int lo = offs[row], hi = offs[row+1];
  float4 acc = {0.f,0.f,0.f,0.f};
  for (int j = lo; j < hi; ++j) {
    int s = eid[j];
    float4 v = *(const float4*)(xw + (size_t)s*CC + lane*4);
    acc.x += v.x; acc.y += v.y; acc.z += v.z; acc.w += v.w;
  }
  float sc = rsqrtf((float)max(hi - lo, 1));
  float4 bb = *(const float4*)(b + lane*4);
  float4 o;
  o.x = acc.x*sc + bb.x; o.y = acc.y*sc + bb.y;
  o.z = acc.z*sc + bb.z; o.w = acc.w*sc + bb.w;
  *(float4*)(out + (size_t)row*CC + lane*4) = o;
}

// ---------------- el/er: per-node per-head attention logits ----------------
template<int H>
__global__ void k_elr(const float* __restrict__ f, const float* __restrict__ al,
                      const float* __restrict__ ar, float* __restrict__ el, float* __restrict__ er) {
  const int D = CC / H;
  int i = blockIdx.x*256 + threadIdx.x;   // over N*H
  if (i >= NN*H) return;
  int n = i / H, h = i % H;
  const float* fr = f + (size_t)n*CC + h*D;
  float a = 0.f, b = 0.f;
  for (int dd = 0; dd < D; ++dd) { float v = fr[dd]; a += v*al[h*D+dd]; b += v*ar[h*D+dd]; }
  el[i] = a; er[i] = b;
}

// ---------------- GAT gather (two passes over in-edges), fused combine+bias+leaky --------
// NOTE: segment-max shift omitted — alpha = ex/sum is shift-invariant; |e| is O(1) here.
template<int H, bool ATT, bool LEAKY>
__global__ void k_gat_gather(const float* __restrict__ f, const int* __restrict__ offs,
                             const int* __restrict__ eid,
                             const float* __restrict__ el, const float* __restrict__ er,
                             const float* __restrict__ bgat, float* __restrict__ out,
                             float* __restrict__ att) {
  int lane = threadIdx.x & 31;
  int row = blockIdx.x*8 + (threadIdx.x >> 5);
  if (row >= NN) return;
  int h = (lane*4) / (CC/H);
  float erd = er[(size_t)row*H + h];
  int lo = offs[row], hi = offs[row+1];
  float denom = 0.f;
  for (int j = lo; j < hi; ++j) {
    int s = eid[j];
    float v = el[s*H+h] + erd;
    v = (v >= 0.f) ? v : 0.2f*v;
    denom += __expf(v);
  }
  float inv = (denom > 0.f) ? 1.0f/denom : 0.f;
  float4 acc = {0.f,0.f,0.f,0.f};
  for (int j = lo; j < hi; ++j) {
    int s = eid[j];
    float v = el[s*H+h] + erd;
    v = (v >= 0.f) ? v : 0.2f*v;
    float alpha = __expf(v) * inv;
    float4 x = *(const float4*)(f + (size_t)s*CC + lane*4);
    acc.x += alpha*x.x; acc.y += alpha*x.y; acc.z += alpha*x.z; acc.w += alpha*x.w;
    if (ATT) { if (lane == 0) atomicAdd(&att[s], alpha); }   // H==1 only
  }
  float4 cur = *(const float4*)(out + (size_t)row*CC + lane*4);
  float4 bb = *(const float4*)(bgat + lane*4);
  float4 o;
  o.x = cur.x + acc.x + bb.x; o.y = cur.y + acc.y + bb.y;
  o.z = cur.z + acc.z + bb.z; o.w = cur.w + acc.w + bb.w;
  if (LEAKY) {
    o.x = (o.x >= 0.f) ? o.x : 0.2f*o.x; o.y = (o.y >= 0.f) ? o.y : 0.2f*o.y;
    o.z = (o.z >= 0.f) ? o.z : 0.2f*o.z; o.w = (o.w >= 0.f) ? o.w : 0.2f*o.w;
  }
  *(float4*)(out + (size_t)row*CC + lane*4) = o;
}

// ---------------- batchnorm stats: per-column sum / sumsq ----------------
__global__ void k_bn_stats(const float* __restrict__ t, float* __restrict__ cs, float* __restrict__ cq) {
  __shared__ float ls[256], lq[256];
  int col = threadIdx.x & 127, half = threadIdx.x >> 7;
  float s = 0.f, q = 0.f;
  for (int r = blockIdx.x*2 + half; r < NN; r += gridDim.x*2) {
    float v = t[(size_t)r*CC + col]; s += v; q += v*v;
  }
  ls[threadIdx.x] = s; lq[threadIdx.x] = q;
  __syncthreads();
  if (half == 0) {
    atomicAdd(&cs[col], ls[threadIdx.x] + ls[threadIdx.x+128]);
    atomicAdd(&cq[col], lq[threadIdx.x] + lq[threadIdx.x+128]);
  }
}

// ---------------- batchnorm apply ----------------
__global__ void k_bn_apply(const float* __restrict__ t, const float* __restrict__ cs,
                           const float* __restrict__ cq, const float* __restrict__ g,
                           const float* __restrict__ be, float* __restrict__ h) {
  int i = blockIdx.x*256 + threadIdx.x;
  if (i >= NN*CC) return;
  int col = i & 127;
  float mu = cs[col] * (1.f/NN);
  float var = cq[col] * (1.f/NN) - mu*mu;
  h[i] = g[col]*(t[i]-mu)*rsqrtf(var + BNEPS) + be[col];
}

// ---------------- pooling using sorted graph_ids: per-graph node range via binary search ----
__global__ void k_pool_csr(const float* __restrict__ h, const float* __restrict__ att,
                           const int* __restrict__ gids, float* __restrict__ frag) {
  int g = blockIdx.x;
  __shared__ int se[2];
  if (threadIdx.x < 2) {
    int target = g + threadIdx.x;
    int lo = 0, hi = NN;
    while (lo < hi) { int mid = (lo + hi) >> 1; if (gids[mid] < target) lo = mid + 1; else hi = mid; }
    se[threadIdx.x] = lo;
  }
  __syncthreads();
  int lo = se[0], hi = se[1];
  int col = threadIdx.x;
  float acc = 0.f;
  for (int n = lo; n < hi; ++n) acc += h[(size_t)n*CC + col] * att[n];
  frag[(size_t)g*CC + col] = acc / (float)max(hi - lo, 1);
}

// ---------------- one full layer ----------------
template<int FIN, int H, bool ATT, bool LEAKY>
static void run_layer(const float* x, const float* Wgc, const float* bgc,
                      const float* Wgat, const float* al, const float* ar, const float* bgat,
                      const float* g, const float* be,
                      const int* offs_i, const int* eid_i, const int* offs_c, const int* eid_c,
                      const int* dout, unsigned short* Wth, unsigned short* Wtl,
                      float* A1, float* A2, float* B, float* Hb, float* el, float* er,
                      float* cs, float* cq, float* att, hipStream_t stream) {
  k_pack_w<FIN><<<cdiv(256*FIN,256), 256, 0, stream>>>(Wgc, Wgat, Wth, Wtl);
  k_gemm2<FIN><<<cdiv(NN,128), 256, 0, stream>>>(x, Wth, Wtl, dout, A1, A2);
  k_gc_gather<<<cdiv(NN,8), 256, 0, stream>>>(A1, offs_i, eid_i, bgc, B);
  k_elr<H><<<cdiv((long)NN*H,256), 256, 0, stream>>>(A2, al, ar, el, er);
  k_gat_gather<H,ATT,LEAKY><<<cdiv(NN,8), 256, 0, stream>>>(A2, offs_c, eid_c, el, er, bgat, B, att);
  hipMemsetAsync(cs, 0, 2*CC*sizeof(float), stream);                      // cs,cq contiguous
  k_bn_stats<<<512, 256, 0, stream>>>(B, cs, cq);
  k_bn_apply<<<cdiv((long)NN*CC,256), 256, 0, stream>>>(B, cs, cq, g, be, Hb);
}

extern "C" void kernel_launch(void* const* d_in, const int* in_sizes, int n_in,
                              void* d_out, int out_size, void* d_ws, size_t ws_size,
                              hipStream_t stream) {
  const float* feat  = (const float*)d_in[0];
  const int* isrc    = (const int*)d_in[1];
  const int* idst    = (const int*)d_in[2];
  const int* csrc    = (const int*)d_in[3];
  const int* cdst    = (const int*)d_in[4];
  const int* gids    = (const int*)d_in[5];
  const float* W_gc1 = (const float*)d_in[6];  const float* b_gc1 = (const float*)d_in[7];
  const float* W_gat1= (const float*)d_in[8];  const float* al1   = (const float*)d_in[9];
  const float* ar1   = (const float*)d_in[10]; const float* b_gat1= (const float*)d_in[11];
  const float* W_gc2 = (const float*)d_in[12]; const float* b_gc2 = (const float*)d_in[13];
  const float* W_gat2= (const float*)d_in[14]; const float* al2   = (const float*)d_in[15];
  const float* ar2   = (const float*)d_in[16]; const float* b_gat2= (const float*)d_in[17];
  const float* W_gc3 = (const float*)d_in[18]; const float* b_gc3 = (const float*)d_in[19];
  const float* W_gat3= (const float*)d_in[20]; const float* al3   = (const float*)d_in[21];
  const float* ar3   = (const float*)d_in[22]; const float* b_gat3= (const float*)d_in[23];
  const float* g1 = (const float*)d_in[24]; const float* be1 = (const float*)d_in[25];
  const float* g2 = (const float*)d_in[26]; const float* be2 = (const float*)d_in[27];
  const float* g3 = (const float*)d_in[28]; const float* be3 = (const float*)d_in[29];

  const size_t NC = (size_t)NN*CC;
  float* A1 = (float*)d_ws;
  float* A2 = A1 + NC;
  float* B  = A2 + NC;
  float* Hb = B  + NC;
  float* el = Hb + NC;            // N*4
  float* er = el + (size_t)NN*4;  // N*4
  float* cs = er + (size_t)NN*4;  // 128
  float* cq = cs + CC;            // 128
  unsigned short* Wth = (unsigned short*)(cq + CC);   // 256*512 bf16
  unsigned short* Wtl = Wth + 256*FDIM;               // 256*512 bf16
  int* offs_i = (int*)(Wtl + 256*FDIM);  // N+1
  int* offs_c = offs_i + (NN+1);  // N+1
  int* deg_i  = offs_c + (NN+1);  // N   (deg_i..dout contiguous: 5N, one memset)
  int* deg_c  = deg_i + NN;       // N
  int* cnt_i  = deg_c + NN;       // N
  int* cnt_c  = cnt_i + NN;       // N
  int* dout   = cnt_c + NN;       // N
  int* eid_i  = dout + NN;        // EI
  int* eid_c  = eid_i + EIE;      // EC

  float* frag = (float*)d_out;        // [G,128]
  float* att  = frag + (size_t)GG*CC; // [N]

  // ---- build CSR (per call; inputs re-poisoned each launch) ----
  hipMemsetAsync(deg_i, 0, 5*(size_t)NN*sizeof(int), stream);
  hipMemsetAsync(att, 0, (size_t)NN*sizeof(float), stream);
  k_count<<<cdiv(EIE,256), 256, 0, stream>>>(isrc, idst, cdst, deg_i, deg_c, dout);
  k_scan2<<<2, 256, 0, stream>>>(deg_i, offs_i, deg_c, offs_c);
  k_fill<<<cdiv(EIE,256), 256, 0, stream>>>(isrc, idst, offs_i, cnt_i, eid_i, EIE);
  k_fill<<<cdiv(ECE,256), 256, 0, stream>>>(csrc, cdst, offs_c, cnt_c, eid_c, ECE);

  // ---- layers ----
  run_layer<FDIM,4,false,true>(feat, W_gc1, b_gc1, W_gat1, al1, ar1, b_gat1, g1, be1,
                               offs_i, eid_i, offs_c, eid_c, dout, Wth, Wtl,
                               A1, A2, B, Hb, el, er, cs, cq, nullptr, stream);
  run_layer<CC,4,false,true>(Hb, W_gc2, b_gc2, W_gat2, al2, ar2, b_gat2, g2, be2,
                             offs_i, eid_i, offs_c, eid_c, dout, Wth, Wtl,
                             A1, A2, B, Hb, el, er, cs, cq, nullptr, stream);
  run_layer<CC,1,true,false>(Hb, W_gc3, b_gc3, W_gat3, al3, ar3, b_gat3, g3, be3,
                             offs_i, eid_i, offs_c, eid_c, dout, Wth, Wtl,
                             A1, A2, B, Hb, el, er, cs, cq, att, stream);

  // ---- pooling (graph_ids sorted) ----
  k_pool_csr<<<GG, 128, 0, stream>>>(Hb, att, gids, frag);
}